// Round 3
// baseline (228.268 us; speedup 1.0000x reference)
//
#include <hip/hip_runtime.h>
#include <math.h>

#define CH 512
#define RED 64

typedef __attribute__((ext_vector_type(4))) float f32x4;
typedef long i64;

typedef const __attribute__((address_space(1))) void* gas_t;
typedef __attribute__((address_space(3))) void* las_t;

static __device__ __forceinline__ void gl16(const void* g, void* l) {
    __builtin_amdgcn_global_load_lds((gas_t)g, (las_t)l, 16, 0, 0);
}

// pack f32 -> fp8 e4m3
static __device__ __forceinline__ unsigned pk4(float a, float b, float c, float d) {
    int w = __builtin_amdgcn_cvt_pk_fp8_f32(a, b, 0, false);
    w = __builtin_amdgcn_cvt_pk_fp8_f32(c, d, w, true);
    return (unsigned)w;
}
static __device__ __forceinline__ unsigned char pk1(float a) {
    return (unsigned char)(__builtin_amdgcn_cvt_pk_fp8_f32(a, a, 0, false) & 0xFF);
}

// hardware exp2 (v_exp_f32 IS base-2)
static __device__ __forceinline__ float fexp2(float v) {
#if __has_builtin(__builtin_amdgcn_exp2f)
    return __builtin_amdgcn_exp2f(v);
#else
    float r; asm("v_exp_f32 %0, %1" : "=v"(r) : "v"(v)); return r;
#endif
}

// raw workgroup barrier with compiler memory fences (no implicit vmcnt(0) drain)
static __device__ __forceinline__ void barrier_raw() {
    asm volatile("" ::: "memory");
    __builtin_amdgcn_s_barrier();
    asm volatile("" ::: "memory");
}

// ---------------------------------------------------------------------------
// prep_w: Wq|Wk|Wv f32 -> Wcat fp8 [640][512]; rows 0-63 q, 64-127 k, 128-639 v.
// ---------------------------------------------------------------------------
__global__ __launch_bounds__(128) void prep_w(
    const float* __restrict__ Wq, const float* __restrict__ Wk,
    const float* __restrict__ Wv, unsigned char* __restrict__ Wcat)
{
    const int r = blockIdx.x, t = threadIdx.x;
    const float* src = (r < 64) ? (Wq + (size_t)r * CH)
                     : (r < 128) ? (Wk + (size_t)(r - 64) * CH)
                                 : (Wv + (size_t)(r - 128) * CH);
    const float4 v = *(const float4*)&src[t * 4];
    *(unsigned*)&Wcat[(size_t)r * CH + t * 4] = pk4(v.x, v.y, v.z, v.w);
}

// ---------------------------------------------------------------------------
// cast_xt: x f32 [b][c][n] -> xT fp8 [b][n][512].  64x64 tiles.
// ---------------------------------------------------------------------------
__global__ __launch_bounds__(256) void cast_xt(
    const float* __restrict__ x, unsigned char* __restrict__ xT, int n)
{
    __shared__ float sX[64][65];
    const int b = blockIdx.z, i0 = blockIdx.x * 64, c0 = blockIdx.y * 64;
    const int t = threadIdx.x;
    #pragma unroll
    for (int s = 0; s < 4; ++s) {
        const int id = s * 256 + t, c = id >> 4, seg = id & 15;
        *(float4*)&sX[c][seg * 4] = *(const float4*)&x[((size_t)b * CH + c0 + c) * n + i0 + seg * 4];
    }
    __syncthreads();
    const int i = t >> 2, cp = t & 3;
    uint4 w;
    w.x = pk4(sX[cp*16+ 0][i], sX[cp*16+ 1][i], sX[cp*16+ 2][i], sX[cp*16+ 3][i]);
    w.y = pk4(sX[cp*16+ 4][i], sX[cp*16+ 5][i], sX[cp*16+ 6][i], sX[cp*16+ 7][i]);
    w.z = pk4(sX[cp*16+ 8][i], sX[cp*16+ 9][i], sX[cp*16+10][i], sX[cp*16+11][i]);
    w.w = pk4(sX[cp*16+12][i], sX[cp*16+13][i], sX[cp*16+14][i], sX[cp*16+15][i]);
    *(uint4*)&xT[((size_t)b * n + i0 + i) * CH + c0 + cp * 16] = w;
}

// ---------------------------------------------------------------------------
// qkv_gemm (fp8): out = xT * Wcat^T + bias.  128i x 128o tiles, K=512.
// q-rows (o<64 at o0==0) are additionally scaled by log2(e) BEFORE fp8
// quantization, so attn/rowmax operate on S' = log2e*S and attn's softmax
// is a single v_exp_f32 (exp2) with no per-element multiply.
// ---------------------------------------------------------------------------
__global__ __launch_bounds__(256, 4) void qkv_gemm(
    const unsigned char* __restrict__ xT, const unsigned char* __restrict__ Wcat,
    const float* __restrict__ bq, const float* __restrict__ bk,
    const float* __restrict__ bv,
    unsigned char* __restrict__ qF, unsigned char* __restrict__ kF,
    unsigned char* __restrict__ v2, int n)
{
    __shared__ char smem[20480];   // sA 128x80 | sB 128x80
    const int b = blockIdx.z, i0 = blockIdx.x * 128, o0 = blockIdx.y * 128;
    const int t = threadIdx.x, lane = t & 63;
    const int quad = lane >> 4, l16 = lane & 15;
    const int wrow = (t >> 6) & 1, wcol = t >> 7;

    f32x4 acc[4][4];
    const f32x4 zz = {0.f, 0.f, 0.f, 0.f};
    #pragma unroll
    for (int mi = 0; mi < 4; ++mi)
        #pragma unroll
        for (int ci = 0; ci < 4; ++ci) acc[mi][ci] = zz;

    const unsigned char* Ab = xT + ((size_t)b * n + i0) * CH;
    const unsigned char* Bb = Wcat + (size_t)o0 * CH;

    for (int c0 = 0; c0 < CH; c0 += 64) {
        #pragma unroll
        for (int s = 0; s < 5; ++s) {
            const int c = s * 256 + t;
            const bool isA = c < 640;
            const int tc = isA ? c : c - 640;
            const int r = tc / 5, p = (tc % 5) & 3;
            gl16((isA ? Ab : Bb) + (size_t)r * CH + c0 + p * 16,
                 smem + (isA ? 0 : 10240) + (size_t)tc * 16);
        }
        __syncthreads();
        #pragma unroll
        for (int kk = 0; kk < 64; kk += 32) {
            i64 af[4], bf[4];
            #pragma unroll
            for (int mi = 0; mi < 4; ++mi)
                af[mi] = *(const i64*)(smem + (wrow * 64 + mi * 16 + l16) * 80 + kk + quad * 8);
            #pragma unroll
            for (int ci = 0; ci < 4; ++ci)
                bf[ci] = *(const i64*)(smem + 10240 + (wcol * 64 + ci * 16 + l16) * 80 + kk + quad * 8);
            #pragma unroll
            for (int mi = 0; mi < 4; ++mi)
                #pragma unroll
                for (int ci = 0; ci < 4; ++ci)
                    acc[mi][ci] = __builtin_amdgcn_mfma_f32_16x16x32_fp8_fp8(af[mi], bf[ci], acc[mi][ci], 0, 0, 0);
        }
        __syncthreads();
    }

    float bb[4], scl[4];
    #pragma unroll
    for (int ci = 0; ci < 4; ++ci) {
        const int o = wcol * 64 + ci * 16 + l16;
        if (o0 == 0) {
            bb[ci]  = (o < 64) ? bq[o] : bk[o - 64];
            scl[ci] = (o < 64) ? 1.44269504088896f : 1.0f;
        } else {
            bb[ci]  = bv[o0 - 128 + o];
            scl[ci] = 1.0f;
        }
    }
    __syncthreads();
    unsigned char* sE = (unsigned char*)smem;    // 128 x 144
    if (o0 == 0) {
        #pragma unroll
        for (int mi = 0; mi < 4; ++mi)
            #pragma unroll
            for (int ci = 0; ci < 4; ++ci)
                #pragma unroll
                for (int r = 0; r < 4; ++r)
                    sE[(wrow*64 + mi*16 + quad*4 + r) * 144 + wcol*64 + ci*16 + l16] =
                        pk1((acc[mi][ci][r] + bb[ci]) * scl[ci]);
    } else {
        #pragma unroll
        for (int mi = 0; mi < 4; ++mi)
            #pragma unroll
            for (int ci = 0; ci < 4; ++ci)
                #pragma unroll
                for (int r = 0; r < 4; ++r)
                    sE[(wcol*64 + ci*16 + l16) * 144 + wrow*64 + mi*16 + quad*4 + r] =
                        pk1(acc[mi][ci][r] + bb[ci]);
    }
    __syncthreads();
    if (o0 == 0) {
        #pragma unroll
        for (int u = 0; u < 2; ++u) {
            const int id = u * 256 + t, i = id >> 2, p = id & 3;
            *(uint4*)&qF[((size_t)b * n + i0 + i) * RED + p * 16] = *(const uint4*)&sE[i * 144 + p * 16];
        }
        #pragma unroll
        for (int u = 0; u < 2; ++u) {
            const int id = u * 256 + t, i = id >> 2, p = id & 3;
            *(uint4*)&kF[((size_t)b * n + i0 + i) * RED + p * 16] = *(const uint4*)&sE[i * 144 + 64 + p * 16];
        }
    } else {
        #pragma unroll
        for (int u = 0; u < 4; ++u) {
            const int id = u * 256 + t, o = id >> 3, p = id & 7;
            *(uint4*)&v2[((size_t)b * CH + (o0 - 128) + o) * n + i0 + p * 16] =
                *(const uint4*)&sE[o * 144 + p * 16];
        }
    }
}

// ---------------------------------------------------------------------------
// rowmax: m_i = max_j S' (bit-identical S' to attn's fp8 MFMA; qF already
// carries the log2e scale so the stored max is in the exp2 domain).
// ---------------------------------------------------------------------------
__global__ __launch_bounds__(256, 4) void rowmax(
    const unsigned char* __restrict__ qF, const unsigned char* __restrict__ kF,
    unsigned* __restrict__ mKey, int n)
{
    __shared__ char smem[20480];
    const int b = blockIdx.z, i0 = blockIdx.y * 128, j0 = blockIdx.x * 128;
    const int t = threadIdx.x, lane = t & 63;
    const int quad = lane >> 4, l16 = lane & 15;
    const int wrow = (t >> 6) & 1, wcol = t >> 7;

    const unsigned char* Qb = qF + ((size_t)b * n + i0) * RED;
    const unsigned char* Kb = kF + ((size_t)b * n + j0) * RED;
    #pragma unroll
    for (int s = 0; s < 5; ++s) {
        const int c = s * 256 + t;
        const bool isQ = c < 640;
        const int tc = isQ ? c : c - 640;
        const int r = tc / 5, p = (tc % 5) & 3;
        gl16((isQ ? Qb : Kb) + (size_t)r * RED + p * 16,
             smem + (isQ ? 0 : 10240) + (size_t)tc * 16);
    }
    __syncthreads();

    f32x4 acc[4][4];
    const f32x4 zz = {0.f, 0.f, 0.f, 0.f};
    #pragma unroll
    for (int mi = 0; mi < 4; ++mi)
        #pragma unroll
        for (int ci = 0; ci < 4; ++ci) acc[mi][ci] = zz;

    #pragma unroll
    for (int kk = 0; kk < 64; kk += 32) {
        i64 af[4], bf[4];
        #pragma unroll
        for (int mi = 0; mi < 4; ++mi)
            af[mi] = *(const i64*)(smem + (wrow * 64 + mi * 16 + l16) * 80 + kk + quad * 8);
        #pragma unroll
        for (int ci = 0; ci < 4; ++ci)
            bf[ci] = *(const i64*)(smem + 10240 + (wcol * 64 + ci * 16 + l16) * 80 + kk + quad * 8);
        #pragma unroll
        for (int mi = 0; mi < 4; ++mi)
            #pragma unroll
            for (int ci = 0; ci < 4; ++ci)
                acc[mi][ci] = __builtin_amdgcn_mfma_f32_16x16x32_fp8_fp8(af[mi], bf[ci], acc[mi][ci], 0, 0, 0);
    }

    #pragma unroll
    for (int mi = 0; mi < 4; ++mi)
        #pragma unroll
        for (int r = 0; r < 4; ++r) {
            float mx = fmaxf(fmaxf(acc[mi][0][r], acc[mi][1][r]),
                             fmaxf(acc[mi][2][r], acc[mi][3][r]));
            #pragma unroll
            for (int off = 1; off < 16; off <<= 1) mx = fmaxf(mx, __shfl_xor(mx, off));
            if (l16 == 0) {
                union { float f; unsigned u; } cv; cv.f = mx;
                const unsigned key = ((int)cv.u >= 0) ? (cv.u + 0x80000000u) : ~cv.u;
                atomicMax(&mKey[(size_t)b * n + i0 + wrow * 64 + mi * 16 + quad * 4 + r], key);
            }
        }
}

// ---------------------------------------------------------------------------
// attn v5: identical geometry + sync structure to v4 (64q x 256ch, counted
// vmcnt, 3-barrier), but ALL per-chunk address arithmetic hoisted:
//  - 4 precomputed per-lane LDS base offsets (fA/vA/pA/pwA); the kki=1
//    k-slice is addr^32 (part bit-1 lives at byte-address bit 5), and
//    ct/qt deltas are compile-time 1024-multiples folding into ds_read imms
//  - chunk loop unrolled x2 so the double-buffer base (0/20480) is a literal
//  - staging uses 3 walking pointers (+=4096 / +=64) instead of full
//    recompute inside a lambda
// Goal: VALUBusy 38% -> ~22% (addr re-materialization was ~140 VALU/chunk
// at VGPR=48); serial per-wave chunk path shortens accordingly.
// ---------------------------------------------------------------------------
#define STGSZ 20480
#define SPOFF 40960
#define SLOFF 45056

#define CHUNK(BASE, cc) do {                                                  \
    f32x4 S_[2] = {zz, zz};                                                   \
    __builtin_amdgcn_s_setprio(1);                                            \
    {                                                                         \
        const i64 kf0 = *(const i64*)(smem + (BASE) + fA);                    \
        const i64 kf1 = *(const i64*)(smem + (BASE) + (fA ^ 32));             \
        S_[0] = __builtin_amdgcn_mfma_f32_16x16x32_fp8_fp8(kf0, qreg[0][0], S_[0], 0, 0, 0); \
        S_[1] = __builtin_amdgcn_mfma_f32_16x16x32_fp8_fp8(kf0, qreg[1][0], S_[1], 0, 0, 0); \
        S_[0] = __builtin_amdgcn_mfma_f32_16x16x32_fp8_fp8(kf1, qreg[0][1], S_[0], 0, 0, 0); \
        S_[1] = __builtin_amdgcn_mfma_f32_16x16x32_fp8_fp8(kf1, qreg[1][1], S_[1], 0, 0, 0); \
    }                                                                         \
    __builtin_amdgcn_s_setprio(0);                                            \
    _Pragma("unroll")                                                         \
    for (int qt = 0; qt < 2; ++qt) {                                          \
        const float e0 = fexp2(S_[qt][0] - mrow[qt]);                         \
        const float e1 = fexp2(S_[qt][1] - mrow[qt]);                         \
        const float e2 = fexp2(S_[qt][2] - mrow[qt]);                         \
        const float e3 = fexp2(S_[qt][3] - mrow[qt]);                         \
        lacc[qt] += (e0 + e1) + (e2 + e3);                                    \
        *(unsigned*)(smem + pwA + qt * 1024) = pk4(e0, e1, e2, e3);           \
    }                                                                         \
    asm volatile("s_waitcnt lgkmcnt(0)" ::: "memory");                        \
    barrier_raw();   /* P visible; chunk cc+1 staging still in flight */      \
    __builtin_amdgcn_s_setprio(1);                                            \
    _Pragma("unroll")                                                         \
    for (int kki = 0; kki < 2; ++kki) {                                       \
        const int kx = kki << 5;                                              \
        i64 vf_[4], pf_[2];                                                   \
        _Pragma("unroll")                                                     \
        for (int ct = 0; ct < 4; ++ct)                                        \
            vf_[ct] = *(const i64*)(smem + (BASE) + (vA ^ kx) + ct * 1024);   \
        _Pragma("unroll")                                                     \
        for (int qt = 0; qt < 2; ++qt)                                        \
            pf_[qt] = *(const i64*)(smem + (pA ^ kx) + qt * 1024);            \
        _Pragma("unroll")                                                     \
        for (int qt = 0; qt < 2; ++qt)                                        \
            _Pragma("unroll")                                                 \
            for (int ct = 0; ct < 4; ++ct)                                    \
                acc[qt][ct] = __builtin_amdgcn_mfma_f32_16x16x32_fp8_fp8(vf_[ct], pf_[qt], acc[qt][ct], 0, 0, 0); \
    }                                                                         \
    __builtin_amdgcn_s_setprio(0);                                            \
    asm volatile("s_waitcnt lgkmcnt(0)" ::: "memory");                        \
    barrier_raw();   /* buffer BASE free, P rewritable */                     \
    if ((cc) + 2 < nchunks) {                                                 \
        if (t < 256) gl16(kP, smem + (BASE) + kDstOff);                       \
        gl16(vP0, smem + (BASE) + vDstOff0);                                  \
        gl16(vP1, smem + (BASE) + vDstOff1);                                  \
        kP += 4096; vP0 += 64; vP1 += 64;                                     \
        if (w < 4) asm volatile("s_waitcnt vmcnt(3)" ::: "memory");           \
        else       asm volatile("s_waitcnt vmcnt(2)" ::: "memory");           \
        __builtin_amdgcn_sched_barrier(0);                                    \
        barrier_raw();   /* chunk cc+1 landed globally */                     \
    } else if ((cc) + 1 < nchunks) {                                          \
        asm volatile("s_waitcnt vmcnt(0)" ::: "memory");                      \
        __builtin_amdgcn_sched_barrier(0);                                    \
        barrier_raw();                                                        \
    }                                                                         \
} while (0)

__global__ __launch_bounds__(512, 4) void attn(
    const unsigned char* __restrict__ qF,   // [b][n][64] fp8 (log2e-scaled)
    const unsigned char* __restrict__ kF,   // [b][n][64] fp8
    const unsigned char* __restrict__ v2,   // [b][512][n] fp8
    const unsigned* __restrict__ mKey,
    const float* __restrict__ x, const float* __restrict__ gamma,
    float* __restrict__ y, int n)
{
    __shared__ char smem[46080];
    const int b = blockIdx.x >> 1, ch0 = (blockIdx.x & 1) * 256;
    const int i0 = blockIdx.y * 64;
    const int t = threadIdx.x, lane = t & 63, w = t >> 6;
    const int quad = lane >> 4, l16 = lane & 15;
    const int qh = w & 1, g = w >> 1;
    const int sw = (l16 >> 1) & 3;          // read-side swizzle key
    const int boff = (quad & 1) * 8;        // byte-in-part for fragments
    const int phalf = quad >> 1;            // part contribution from quad
    const int p0 = phalf ^ sw;              // kki=0 stored part

    // per-lane invariant LDS byte offsets (kki=1 slice = offset ^ 32)
    const int fA  = (g * 16 + l16) * 64 + p0 * 16 + boff;           // S-phase K frag
    const int vA  = 4096 + (g * 64 + l16) * 64 + p0 * 16 + boff;    // PV V frag (+ct*1024)
    const int pA  = SPOFF + (qh * 32 + l16) * 64 + p0 * 16 + boff;  // PV P frag (+qt*1024)
    const int pwA = SPOFF + (qh * 32 + l16) * 64 + (g ^ sw) * 16 + quad * 4; // P write (+qt*1024)

    const unsigned char* Qb = qF + ((size_t)b * n + i0) * RED;
    const unsigned char* Kb = kF + (size_t)b * n * RED;
    const unsigned char* Vb = v2 + ((size_t)b * CH + ch0) * n;

    // staging geometry (source side carries the XOR swizzle; dst is linear)
    const int r = t >> 2, s4 = t & 3, gs = s4 ^ ((r >> 1) & 3);
    const int kDstOff  = t * 16;
    const int vDstOff0 = 4096 + t * 16;
    const int vDstOff1 = 12288 + t * 16;
    const size_t vHalf = (size_t)128 * n;
    const unsigned char* kSrc0 = Kb + (size_t)r * RED + gs * 16;
    const unsigned char* vSrc0 = Vb + (size_t)r * n + gs * 16;

    // ---- prologue: stage Q + chunk 0; load mrow early
    if (t < 256) {
        gl16(Qb + (size_t)r * RED + gs * 16, smem + SPOFF + kDstOff);
        gl16(kSrc0, smem + kDstOff);
    }
    gl16(vSrc0, smem + vDstOff0);
    gl16(vSrc0 + vHalf, smem + vDstOff1);

    float mrow[2];
    #pragma unroll
    for (int qt = 0; qt < 2; ++qt) {
        const unsigned u = mKey[(size_t)b * n + i0 + qh * 32 + qt * 16 + l16];
        const unsigned bits = (u >= 0x80000000u) ? (u - 0x80000000u) : ~u;
        union { unsigned u; float f; } cv; cv.u = bits;
        mrow[qt] = cv.f;
    }
    __syncthreads();   // full drain: Q + chunk0 ready (once per kernel)

    // ---- preload Q fragments (B-operand layout: lane=q-col, bytes=red)
    i64 qreg[2][2];
    #pragma unroll
    for (int qt = 0; qt < 2; ++qt) {
        #pragma unroll
        for (int kki = 0; kki < 2; ++kki)
            qreg[qt][kki] = *(const i64*)(smem + ((pA ^ (kki << 5)) + qt * 1024));
    }
    asm volatile("s_waitcnt lgkmcnt(0)" ::: "memory");
    barrier_raw();     // all Q-frag reads done before any P write

    const int nchunks = n >> 6;   // 64 (even) for n=4096
    if (nchunks > 1) {            // chunk 1 in flight across chunk 0
        if (t < 256) gl16(kSrc0 + 4096, smem + STGSZ + kDstOff);
        gl16(vSrc0 + 64, smem + STGSZ + vDstOff0);
        gl16(vSrc0 + vHalf + 64, smem + STGSZ + vDstOff1);
    }
    const unsigned char* kP  = kSrc0 + 8192;
    const unsigned char* vP0 = vSrc0 + 128;
    const unsigned char* vP1 = vSrc0 + vHalf + 128;

    f32x4 acc[2][4];
    const f32x4 zz = {0.f, 0.f, 0.f, 0.f};
    #pragma unroll
    for (int qt = 0; qt < 2; ++qt)
        #pragma unroll
        for (int ct = 0; ct < 4; ++ct) acc[qt][ct] = zz;
    float lacc[2] = {0.f, 0.f};

    for (int c = 0; c < nchunks; c += 2) {
        CHUNK(0, c);
        CHUNK(STGSZ, c + 1);
    }

    // ---- l reduction: over quads (shfl), then over the 4 g-waves (LDS)
    float* sL = (float*)(smem + SLOFF);   // [8 waves][32]
    #pragma unroll
    for (int qt = 0; qt < 2; ++qt) {
        float v = lacc[qt];
        v += __shfl_xor(v, 16);
        v += __shfl_xor(v, 32);
        lacc[qt] = v;
    }
    if (quad == 0) {
        #pragma unroll
        for (int qt = 0; qt < 2; ++qt) sL[w * 32 + qt * 16 + l16] = lacc[qt];
    }
    __syncthreads();
    float il[2];
    #pragma unroll
    for (int qt = 0; qt < 2; ++qt) {
        const int idx = qt * 16 + l16;
        il[qt] = 1.0f / (sL[qh * 32 + idx] + sL[(2 + qh) * 32 + idx] +
                         sL[(4 + qh) * 32 + idx] + sL[(6 + qh) * 32 + idx]);
    }

    // ---- epilogue: 4 rounds of 64 channels; transpose via LDS, y = g*(O/l)+x
    const float gm = gamma[0];
    float* sT = (float*)smem;   // [64][68] f32 = 17.4 KB (aliases buf0)
    #pragma unroll
    for (int cr = 0; cr < 4; ++cr) {
        __syncthreads();
        if (g == cr) {
            #pragma unroll
            for (int ct = 0; ct < 4; ++ct)
                #pragma unroll
                for (int qt = 0; qt < 2; ++qt)
                    #pragma unroll
                    for (int rr = 0; rr < 4; ++rr)
                        sT[(ct * 16 + quad * 4 + rr) * 68 + qh * 32 + qt * 16 + l16] =
                            acc[qt][ct][rr] * il[qt];
        }
        __syncthreads();
        const int row = t >> 3, seg = (t & 7) * 8;
        const size_t gb = ((size_t)b * CH + ch0 + cr * 64 + row) * n + i0 + seg;
        #pragma unroll
        for (int u = 0; u < 2; ++u) {
            const float4 xv = *(const float4*)&x[gb + u * 4];
            const float* op = &sT[row * 68 + seg + u * 4];
            float4 yv;
            yv.x = gm * op[0] + xv.x;
            yv.y = gm * op[1] + xv.y;
            yv.z = gm * op[2] + xv.z;
            yv.w = gm * op[3] + xv.w;
            *(float4*)&y[gb + u * 4] = yv;
        }
    }
}

// ---------------------------------------------------------------------------
extern "C" void kernel_launch(void* const* d_in, const int* in_sizes, int n_in,
                              void* d_out, int out_size, void* d_ws, size_t ws_size,
                              hipStream_t stream) {
    const float* x     = (const float*)d_in[0];
    const float* Wq    = (const float*)d_in[1];
    const float* bq    = (const float*)d_in[2];
    const float* Wk    = (const float*)d_in[3];
    const float* bk    = (const float*)d_in[4];
    const float* Wv    = (const float*)d_in[5];
    const float* bv    = (const float*)d_in[6];
    const float* gamma = (const float*)d_in[7];
    float* y = (float*)d_out;

    const int N = 64 * 64;
    const int B = in_sizes[0] / (CH * N);   // = 4

    char* ws = (char*)d_ws;
    unsigned char* xT   = (unsigned char*)ws;  ws += (size_t)B * N * CH;
    unsigned char* qF   = (unsigned char*)ws;  ws += (size_t)B * N * RED;
    unsigned char* kF   = (unsigned char*)ws;  ws += (size_t)B * N * RED;
    unsigned char* v2   = (unsigned char*)ws;  ws += (size_t)B * CH * N;
    unsigned char* Wcat = (unsigned char*)ws;  ws += (size_t)640 * CH;
    unsigned* mKey      = (unsigned*)ws;

    hipMemsetAsync(mKey, 0, (size_t)B * N * 4, stream);

    prep_w<<<dim3(640), 128, 0, stream>>>(Wq, Wk, Wv, Wcat);
    cast_xt<<<dim3(N / 64, CH / 64, B), 256, 0, stream>>>(x, xT, N);
    qkv_gemm<<<dim3(N / 128, 5, B), 256, 0, stream>>>(xT, Wcat, bq, bk, bv, qF, kF, v2, N);
    rowmax<<<dim3(N / 128, N / 128, B), 256, 0, stream>>>(qF, kF, mKey, N);
    attn<<<dim3(2 * B, N / 64), 512, 0, stream>>>(qF, kF, v2, mKey, x, gamma, y, N);
}

// Round 5
// 227.529 us; speedup vs baseline: 1.0032x; 1.0032x over previous
//
#include <hip/hip_runtime.h>
#include <math.h>

#define CH 512
#define RED 64

typedef __attribute__((ext_vector_type(4))) float f32x4;
typedef long i64;

typedef const __attribute__((address_space(1))) void* gas_t;
typedef __attribute__((address_space(3))) void* las_t;

static __device__ __forceinline__ void gl16(const void* g, void* l) {
    __builtin_amdgcn_global_load_lds((gas_t)g, (las_t)l, 16, 0, 0);
}

// pack f32 -> fp8 e4m3
static __device__ __forceinline__ unsigned pk4(float a, float b, float c, float d) {
    int w = __builtin_amdgcn_cvt_pk_fp8_f32(a, b, 0, false);
    w = __builtin_amdgcn_cvt_pk_fp8_f32(c, d, w, true);
    return (unsigned)w;
}
static __device__ __forceinline__ unsigned char pk1(float a) {
    return (unsigned char)(__builtin_amdgcn_cvt_pk_fp8_f32(a, a, 0, false) & 0xFF);
}

// hardware exp2 (v_exp_f32 IS base-2)
static __device__ __forceinline__ float fexp2(float v) {
#if __has_builtin(__builtin_amdgcn_exp2f)
    return __builtin_amdgcn_exp2f(v);
#else
    float r; asm("v_exp_f32 %0, %1" : "=v"(r) : "v"(v)); return r;
#endif
}

// raw workgroup barrier with compiler memory fences (no implicit vmcnt(0) drain)
static __device__ __forceinline__ void barrier_raw() {
    asm volatile("" ::: "memory");
    __builtin_amdgcn_s_barrier();
    asm volatile("" ::: "memory");
}

// ---------------------------------------------------------------------------
// prep_w: Wq|Wk|Wv f32 -> Wcat fp8 [640][512]; rows 0-63 q, 64-127 k, 128-639 v.
// ---------------------------------------------------------------------------
__global__ __launch_bounds__(128) void prep_w(
    const float* __restrict__ Wq, const float* __restrict__ Wk,
    const float* __restrict__ Wv, unsigned char* __restrict__ Wcat)
{
    const int r = blockIdx.x, t = threadIdx.x;
    const float* src = (r < 64) ? (Wq + (size_t)r * CH)
                     : (r < 128) ? (Wk + (size_t)(r - 64) * CH)
                                 : (Wv + (size_t)(r - 128) * CH);
    const float4 v = *(const float4*)&src[t * 4];
    *(unsigned*)&Wcat[(size_t)r * CH + t * 4] = pk4(v.x, v.y, v.z, v.w);
}

// ---------------------------------------------------------------------------
// cast_xt: x f32 [b][c][n] -> xT fp8 [b][n][512].  64x64 tiles.
// ---------------------------------------------------------------------------
__global__ __launch_bounds__(256) void cast_xt(
    const float* __restrict__ x, unsigned char* __restrict__ xT, int n)
{
    __shared__ float sX[64][65];
    const int b = blockIdx.z, i0 = blockIdx.x * 64, c0 = blockIdx.y * 64;
    const int t = threadIdx.x;
    #pragma unroll
    for (int s = 0; s < 4; ++s) {
        const int id = s * 256 + t, c = id >> 4, seg = id & 15;
        *(float4*)&sX[c][seg * 4] = *(const float4*)&x[((size_t)b * CH + c0 + c) * n + i0 + seg * 4];
    }
    __syncthreads();
    const int i = t >> 2, cp = t & 3;
    uint4 w;
    w.x = pk4(sX[cp*16+ 0][i], sX[cp*16+ 1][i], sX[cp*16+ 2][i], sX[cp*16+ 3][i]);
    w.y = pk4(sX[cp*16+ 4][i], sX[cp*16+ 5][i], sX[cp*16+ 6][i], sX[cp*16+ 7][i]);
    w.z = pk4(sX[cp*16+ 8][i], sX[cp*16+ 9][i], sX[cp*16+10][i], sX[cp*16+11][i]);
    w.w = pk4(sX[cp*16+12][i], sX[cp*16+13][i], sX[cp*16+14][i], sX[cp*16+15][i]);
    *(uint4*)&xT[((size_t)b * n + i0 + i) * CH + c0 + cp * 16] = w;
}

// ---------------------------------------------------------------------------
// qkv_gemm (fp8): out = xT * Wcat^T + bias.  128i x 128o tiles, K=512.
// q-rows scaled by log2(e) before fp8 quantization -> attn softmax is a
// single v_exp_f32 (exp2 domain).
// ---------------------------------------------------------------------------
__global__ __launch_bounds__(256, 4) void qkv_gemm(
    const unsigned char* __restrict__ xT, const unsigned char* __restrict__ Wcat,
    const float* __restrict__ bq, const float* __restrict__ bk,
    const float* __restrict__ bv,
    unsigned char* __restrict__ qF, unsigned char* __restrict__ kF,
    unsigned char* __restrict__ v2, int n)
{
    __shared__ char smem[20480];   // sA 128x80 | sB 128x80
    const int b = blockIdx.z, i0 = blockIdx.x * 128, o0 = blockIdx.y * 128;
    const int t = threadIdx.x, lane = t & 63;
    const int quad = lane >> 4, l16 = lane & 15;
    const int wrow = (t >> 6) & 1, wcol = t >> 7;

    f32x4 acc[4][4];
    const f32x4 zz = {0.f, 0.f, 0.f, 0.f};
    #pragma unroll
    for (int mi = 0; mi < 4; ++mi)
        #pragma unroll
        for (int ci = 0; ci < 4; ++ci) acc[mi][ci] = zz;

    const unsigned char* Ab = xT + ((size_t)b * n + i0) * CH;
    const unsigned char* Bb = Wcat + (size_t)o0 * CH;

    for (int c0 = 0; c0 < CH; c0 += 64) {
        #pragma unroll
        for (int s = 0; s < 5; ++s) {
            const int c = s * 256 + t;
            const bool isA = c < 640;
            const int tc = isA ? c : c - 640;
            const int r = tc / 5, p = (tc % 5) & 3;
            gl16((isA ? Ab : Bb) + (size_t)r * CH + c0 + p * 16,
                 smem + (isA ? 0 : 10240) + (size_t)tc * 16);
        }
        __syncthreads();
        #pragma unroll
        for (int kk = 0; kk < 64; kk += 32) {
            i64 af[4], bf[4];
            #pragma unroll
            for (int mi = 0; mi < 4; ++mi)
                af[mi] = *(const i64*)(smem + (wrow * 64 + mi * 16 + l16) * 80 + kk + quad * 8);
            #pragma unroll
            for (int ci = 0; ci < 4; ++ci)
                bf[ci] = *(const i64*)(smem + 10240 + (wcol * 64 + ci * 16 + l16) * 80 + kk + quad * 8);
            #pragma unroll
            for (int mi = 0; mi < 4; ++mi)
                #pragma unroll
                for (int ci = 0; ci < 4; ++ci)
                    acc[mi][ci] = __builtin_amdgcn_mfma_f32_16x16x32_fp8_fp8(af[mi], bf[ci], acc[mi][ci], 0, 0, 0);
        }
        __syncthreads();
    }

    float bb[4], scl[4];
    #pragma unroll
    for (int ci = 0; ci < 4; ++ci) {
        const int o = wcol * 64 + ci * 16 + l16;
        if (o0 == 0) {
            bb[ci]  = (o < 64) ? bq[o] : bk[o - 64];
            scl[ci] = (o < 64) ? 1.44269504088896f : 1.0f;
        } else {
            bb[ci]  = bv[o0 - 128 + o];
            scl[ci] = 1.0f;
        }
    }
    __syncthreads();
    unsigned char* sE = (unsigned char*)smem;    // 128 x 144
    if (o0 == 0) {
        #pragma unroll
        for (int mi = 0; mi < 4; ++mi)
            #pragma unroll
            for (int ci = 0; ci < 4; ++ci)
                #pragma unroll
                for (int r = 0; r < 4; ++r)
                    sE[(wrow*64 + mi*16 + quad*4 + r) * 144 + wcol*64 + ci*16 + l16] =
                        pk1((acc[mi][ci][r] + bb[ci]) * scl[ci]);
    } else {
        #pragma unroll
        for (int mi = 0; mi < 4; ++mi)
            #pragma unroll
            for (int ci = 0; ci < 4; ++ci)
                #pragma unroll
                for (int r = 0; r < 4; ++r)
                    sE[(wcol*64 + ci*16 + l16) * 144 + wrow*64 + mi*16 + quad*4 + r] =
                        pk1(acc[mi][ci][r] + bb[ci]);
    }
    __syncthreads();
    if (o0 == 0) {
        #pragma unroll
        for (int u = 0; u < 2; ++u) {
            const int id = u * 256 + t, i = id >> 2, p = id & 3;
            *(uint4*)&qF[((size_t)b * n + i0 + i) * RED + p * 16] = *(const uint4*)&sE[i * 144 + p * 16];
        }
        #pragma unroll
        for (int u = 0; u < 2; ++u) {
            const int id = u * 256 + t, i = id >> 2, p = id & 3;
            *(uint4*)&kF[((size_t)b * n + i0 + i) * RED + p * 16] = *(const uint4*)&sE[i * 144 + 64 + p * 16];
        }
    } else {
        #pragma unroll
        for (int u = 0; u < 4; ++u) {
            const int id = u * 256 + t, o = id >> 3, p = id & 7;
            *(uint4*)&v2[((size_t)b * CH + (o0 - 128) + o) * n + i0 + p * 16] =
                *(const uint4*)&sE[o * 144 + p * 16];
        }
    }
}

// ---------------------------------------------------------------------------
// attn v7: v5's PROVEN skeleton (64q x 256ch, double buffer, counted-vmcnt
// staging) + ONLINE row-max folded in as one extra barrier phase per chunk
// (rowmax kernel + mKey deleted).  Per chunk:
//   S -> quad-shfl max -> sMx write -> lgkm+barrier(BA)
//     -> sMx read, m=max(m,cd), rescale acc/lacc by 2^(m_old-m),
//        P=exp2(S-m) write -> lgkm+barrier(B2)
//     -> PV -> lgkm+barrier(B3) -> stage(c+2) + counted vmcnt + barrier(B1)
// P and PV stay in the SAME iteration (flash invariant is local: rescale
// precedes the same-chunk PV add).  sMx (1KB) aliases the post-loop sL
// region (separated by B2+B3 of the final chunk).
// ---------------------------------------------------------------------------
#define STGSZ 20480
#define SPOFF 40960
#define SLOFF 45056

#define CHUNK(BASE, cc) do {                                                  \
    f32x4 S0 = zz, S1 = zz;                                                   \
    __builtin_amdgcn_s_setprio(1);                                            \
    {                                                                         \
        const i64 kf0 = *(const i64*)(smem + (BASE) + fA);                    \
        const i64 kf1 = *(const i64*)(smem + (BASE) + (fA ^ 32));             \
        S0 = __builtin_amdgcn_mfma_f32_16x16x32_fp8_fp8(kf0, qreg[0][0], S0, 0, 0, 0); \
        S1 = __builtin_amdgcn_mfma_f32_16x16x32_fp8_fp8(kf0, qreg[1][0], S1, 0, 0, 0); \
        S0 = __builtin_amdgcn_mfma_f32_16x16x32_fp8_fp8(kf1, qreg[0][1], S0, 0, 0, 0); \
        S1 = __builtin_amdgcn_mfma_f32_16x16x32_fp8_fp8(kf1, qreg[1][1], S1, 0, 0, 0); \
    }                                                                         \
    __builtin_amdgcn_s_setprio(0);                                            \
    /* ---- chunk-max exchange (wave covers 16 j's; union over g via LDS) */  \
    float c0 = fmaxf(fmaxf(S0[0], S0[1]), fmaxf(S0[2], S0[3]));               \
    float c1 = fmaxf(fmaxf(S1[0], S1[1]), fmaxf(S1[2], S1[3]));               \
    c0 = fmaxf(c0, __shfl_xor(c0, 16)); c0 = fmaxf(c0, __shfl_xor(c0, 32));   \
    c1 = fmaxf(c1, __shfl_xor(c1, 16)); c1 = fmaxf(c1, __shfl_xor(c1, 32));   \
    if (quad == 0) {                                                          \
        *(float*)(smem + mxW) = c0;                                           \
        *(float*)(smem + mxW + 256) = c1;                                     \
    }                                                                         \
    asm volatile("s_waitcnt lgkmcnt(0)" ::: "memory");                        \
    barrier_raw();   /* BA: sMx visible to all waves */                       \
    {                                                                         \
        const f32x4 mx0 = *(const f32x4*)(smem + mxR);                        \
        const f32x4 mx1 = *(const f32x4*)(smem + mxR + 256);                  \
        const float cd0 = fmaxf(fmaxf(mx0[0], mx0[1]), fmaxf(mx0[2], mx0[3]));\
        const float cd1 = fmaxf(fmaxf(mx1[0], mx1[1]), fmaxf(mx1[2], mx1[3]));\
        const float mn0 = fmaxf(mold[0], cd0), mn1 = fmaxf(mold[1], cd1);     \
        const float rs0 = fexp2(mold[0] - mn0), rs1 = fexp2(mold[1] - mn1);   \
        mold[0] = mn0; mold[1] = mn1;                                         \
        const float e00 = fexp2(S0[0] - mn0), e01 = fexp2(S0[1] - mn0);       \
        const float e02 = fexp2(S0[2] - mn0), e03 = fexp2(S0[3] - mn0);       \
        lacc[0] = lacc[0] * rs0 + ((e00 + e01) + (e02 + e03));                \
        *(unsigned*)(smem + pwA) = pk4(e00, e01, e02, e03);                   \
        const float e10 = fexp2(S1[0] - mn1), e11 = fexp2(S1[1] - mn1);       \
        const float e12 = fexp2(S1[2] - mn1), e13 = fexp2(S1[3] - mn1);       \
        lacc[1] = lacc[1] * rs1 + ((e10 + e11) + (e12 + e13));                \
        *(unsigned*)(smem + pwA + 1024) = pk4(e10, e11, e12, e13);            \
        _Pragma("unroll")                                                     \
        for (int ct = 0; ct < 4; ++ct)                                        \
            _Pragma("unroll")                                                 \
            for (int rr = 0; rr < 4; ++rr) {                                  \
                acc[0][ct][rr] *= rs0;                                        \
                acc[1][ct][rr] *= rs1;                                        \
            }                                                                 \
    }                                                                         \
    asm volatile("s_waitcnt lgkmcnt(0)" ::: "memory");                        \
    barrier_raw();   /* B2: P visible; staging (cc+1) still in flight */      \
    __builtin_amdgcn_s_setprio(1);                                            \
    _Pragma("unroll")                                                         \
    for (int kki = 0; kki < 2; ++kki) {                                       \
        const int kx = kki << 5;                                              \
        i64 vf_[4], pf_[2];                                                   \
        _Pragma("unroll")                                                     \
        for (int ct = 0; ct < 4; ++ct)                                        \
            vf_[ct] = *(const i64*)(smem + (BASE) + (vA ^ kx) + ct * 1024);   \
        _Pragma("unroll")                                                     \
        for (int qt = 0; qt < 2; ++qt)                                        \
            pf_[qt] = *(const i64*)(smem + (pA ^ kx) + qt * 1024);            \
        _Pragma("unroll")                                                     \
        for (int qt = 0; qt < 2; ++qt)                                        \
            _Pragma("unroll")                                                 \
            for (int ct = 0; ct < 4; ++ct)                                    \
                acc[qt][ct] = __builtin_amdgcn_mfma_f32_16x16x32_fp8_fp8(vf_[ct], pf_[qt], acc[qt][ct], 0, 0, 0); \
    }                                                                         \
    __builtin_amdgcn_s_setprio(0);                                            \
    asm volatile("s_waitcnt lgkmcnt(0)" ::: "memory");                        \
    barrier_raw();   /* B3: buffer BASE free, P rewritable */                 \
    if ((cc) + 2 < nchunks) {                                                 \
        if (t < 256) gl16(kP, smem + (BASE) + kDstOff);                       \
        gl16(vP0, smem + (BASE) + vDstOff0);                                  \
        gl16(vP1, smem + (BASE) + vDstOff1);                                  \
        kP += 4096; vP0 += 64; vP1 += 64;                                     \
        if (w < 4) asm volatile("s_waitcnt vmcnt(3)" ::: "memory");           \
        else       asm volatile("s_waitcnt vmcnt(2)" ::: "memory");           \
        __builtin_amdgcn_sched_barrier(0);                                    \
        barrier_raw();   /* B1: chunk cc+1 landed globally */                 \
    } else if ((cc) + 1 < nchunks) {                                          \
        asm volatile("s_waitcnt vmcnt(0)" ::: "memory");                      \
        __builtin_amdgcn_sched_barrier(0);                                    \
        barrier_raw();                                                        \
    }                                                                         \
} while (0)

__global__ __launch_bounds__(512, 4) void attn(
    const unsigned char* __restrict__ qF,   // [b][n][64] fp8 (log2e-scaled)
    const unsigned char* __restrict__ kF,   // [b][n][64] fp8
    const unsigned char* __restrict__ v2,   // [b][512][n] fp8
    const float* __restrict__ x, const float* __restrict__ gamma,
    float* __restrict__ y, int n)
{
    __shared__ char smem[46080];
    const int b = blockIdx.x >> 1, ch0 = (blockIdx.x & 1) * 256;
    const int i0 = blockIdx.y * 64;
    const int t = threadIdx.x, lane = t & 63, w = t >> 6;
    const int quad = lane >> 4, l16 = lane & 15;
    const int qh = w & 1, g = w >> 1;
    const int sw = (l16 >> 1) & 3;          // read-side swizzle key
    const int boff = (quad & 1) * 8;        // byte-in-part for fragments
    const int phalf = quad >> 1;            // part contribution from quad
    const int p0 = phalf ^ sw;              // kki=0 stored part

    // per-lane invariant LDS byte offsets (kki=1 slice = offset ^ 32)
    const int fA  = (g * 16 + l16) * 64 + p0 * 16 + boff;           // S-phase K frag
    const int vA  = 4096 + (g * 64 + l16) * 64 + p0 * 16 + boff;    // PV V frag (+ct*1024)
    const int pA  = SPOFF + (qh * 32 + l16) * 64 + p0 * 16 + boff;  // PV P frag (+qt*1024)
    const int pwA = SPOFF + (qh * 32 + l16) * 64 + (g ^ sw) * 16 + quad * 4; // P write (+qt*1024)
    const int mxR = SLOFF + qh * 512 + l16 * 16;                    // sMx read (g vector)
    const int mxW = mxR + g * 4;                                    // sMx write (quad0 lanes)

    const unsigned char* Qb = qF + ((size_t)b * n + i0) * RED;
    const unsigned char* Kb = kF + (size_t)b * n * RED;
    const unsigned char* Vb = v2 + ((size_t)b * CH + ch0) * n;

    // staging geometry (source side carries the XOR swizzle; dst is linear)
    const int r = t >> 2, s4 = t & 3, gs = s4 ^ ((r >> 1) & 3);
    const int kDstOff  = t * 16;
    const int vDstOff0 = 4096 + t * 16;
    const int vDstOff1 = 12288 + t * 16;
    const size_t vHalf = (size_t)128 * n;
    const unsigned char* kSrc0 = Kb + (size_t)r * RED + gs * 16;
    const unsigned char* vSrc0 = Vb + (size_t)r * n + gs * 16;

    // ---- prologue: stage Q + chunk 0 (full drain via __syncthreads)
    if (t < 256) {
        gl16(Qb + (size_t)r * RED + gs * 16, smem + SPOFF + kDstOff);
        gl16(kSrc0, smem + kDstOff);
    }
    gl16(vSrc0, smem + vDstOff0);
    gl16(vSrc0 + vHalf, smem + vDstOff1);
    __syncthreads();   // full drain: Q + chunk0 ready (once per kernel)

    // ---- preload Q fragments (B-operand layout: lane=q-col, bytes=red)
    i64 qreg[2][2];
    #pragma unroll
    for (int qt = 0; qt < 2; ++qt) {
        #pragma unroll
        for (int kki = 0; kki < 2; ++kki)
            qreg[qt][kki] = *(const i64*)(smem + ((pA ^ (kki << 5)) + qt * 1024));
    }
    asm volatile("s_waitcnt lgkmcnt(0)" ::: "memory");
    barrier_raw();     // all Q-frag reads done before any P write

    const int nchunks = n >> 6;   // 64 (even) for n=4096
    if (nchunks > 1) {            // chunk 1 in flight across chunk 0
        if (t < 256) gl16(kSrc0 + 4096, smem + STGSZ + kDstOff);
        gl16(vSrc0 + 64, smem + STGSZ + vDstOff0);
        gl16(vSrc0 + vHalf + 64, smem + STGSZ + vDstOff1);
    }
    const unsigned char* kP  = kSrc0 + 8192;
    const unsigned char* vP0 = vSrc0 + 128;
    const unsigned char* vP1 = vSrc0 + vHalf + 128;

    f32x4 acc[2][4];
    const f32x4 zz = {0.f, 0.f, 0.f, 0.f};
    #pragma unroll
    for (int qt = 0; qt < 2; ++qt)
        #pragma unroll
        for (int ct = 0; ct < 4; ++ct) acc[qt][ct] = zz;
    float lacc[2] = {0.f, 0.f};
    float mold[2] = {-3.0e38f, -3.0e38f};

    for (int c = 0; c < nchunks; c += 2) {
        CHUNK(0, c);
        CHUNK(STGSZ, c + 1);
    }

    // ---- l reduction: over quads (shfl), then over the 4 g-waves (LDS)
    float* sL = (float*)(smem + SLOFF);   // [8 waves][32] (aliases sMx; safe post-loop)
    #pragma unroll
    for (int qt = 0; qt < 2; ++qt) {
        float v = lacc[qt];
        v += __shfl_xor(v, 16);
        v += __shfl_xor(v, 32);
        lacc[qt] = v;
    }
    __syncthreads();   // all in-loop sMx reads done before sL overwrite
    if (quad == 0) {
        #pragma unroll
        for (int qt = 0; qt < 2; ++qt) sL[w * 32 + qt * 16 + l16] = lacc[qt];
    }
    __syncthreads();
    float il[2];
    #pragma unroll
    for (int qt = 0; qt < 2; ++qt) {
        const int idx = qt * 16 + l16;
        il[qt] = 1.0f / (sL[qh * 32 + idx] + sL[(2 + qh) * 32 + idx] +
                         sL[(4 + qh) * 32 + idx] + sL[(6 + qh) * 32 + idx]);
    }

    // ---- epilogue: 4 rounds of 64 channels; transpose via LDS, y = g*(O/l)+x
    const float gm = gamma[0];
    float* sT = (float*)smem;   // [64][68] f32 = 17.4 KB (aliases buf0)
    #pragma unroll
    for (int cr = 0; cr < 4; ++cr) {
        __syncthreads();
        if (g == cr) {
            #pragma unroll
            for (int ct = 0; ct < 4; ++ct)
                #pragma unroll
                for (int qt = 0; qt < 2; ++qt)
                    #pragma unroll
                    for (int rr = 0; rr < 4; ++rr)
                        sT[(ct * 16 + quad * 4 + rr) * 68 + qh * 32 + qt * 16 + l16] =
                            acc[qt][ct][rr] * il[qt];
        }
        __syncthreads();
        const int row = t >> 3, seg = (t & 7) * 8;
        const size_t gb = ((size_t)b * CH + ch0 + cr * 64 + row) * n + i0 + seg;
        #pragma unroll
        for (int u = 0; u < 2; ++u) {
            const float4 xv = *(const float4*)&x[gb + u * 4];
            const float* op = &sT[row * 68 + seg + u * 4];
            float4 yv;
            yv.x = gm * op[0] + xv.x;
            yv.y = gm * op[1] + xv.y;
            yv.z = gm * op[2] + xv.z;
            yv.w = gm * op[3] + xv.w;
            *(float4*)&y[gb + u * 4] = yv;
        }
    }
}

// ---------------------------------------------------------------------------
extern "C" void kernel_launch(void* const* d_in, const int* in_sizes, int n_in,
                              void* d_out, int out_size, void* d_ws, size_t ws_size,
                              hipStream_t stream) {
    const float* x     = (const float*)d_in[0];
    const float* Wq    = (const float*)d_in[1];
    const float* bq    = (const float*)d_in[2];
    const float* Wk    = (const float*)d_in[3];
    const float* bk    = (const float*)d_in[4];
    const float* Wv    = (const float*)d_in[5];
    const float* bv    = (const float*)d_in[6];
    const float* gamma = (const float*)d_in[7];
    float* y = (float*)d_out;

    const int N = 64 * 64;
    const int B = in_sizes[0] / (CH * N);   // = 4

    char* ws = (char*)d_ws;
    unsigned char* xT   = (unsigned char*)ws;  ws += (size_t)B * N * CH;
    unsigned char* qF   = (unsigned char*)ws;  ws += (size_t)B * N * RED;
    unsigned char* kF   = (unsigned char*)ws;  ws += (size_t)B * N * RED;
    unsigned char* v2   = (unsigned char*)ws;  ws += (size_t)B * CH * N;
    unsigned char* Wcat = (unsigned char*)ws;

    prep_w<<<dim3(640), 128, 0, stream>>>(Wq, Wk, Wv, Wcat);
    cast_xt<<<dim3(N / 64, CH / 64, B), 256, 0, stream>>>(x, xT, N);
    qkv_gemm<<<dim3(N / 128, 5, B), 256, 0, stream>>>(xT, Wcat, bq, bk, bv, qF, kF, v2, N);
    attn<<<dim3(2 * B, N / 64), 512, 0, stream>>>(qF, kF, v2, x, gamma, y, N);
}